// Round 2
// baseline (1010.033 us; speedup 1.0000x reference)
//
#include <hip/hip_runtime.h>
#include <cstddef>

typedef unsigned short u16;
typedef __attribute__((ext_vector_type(8))) short bf16x8;
typedef __attribute__((ext_vector_type(4))) float f32x4;

constexpr int nB = 8, nC = 256, nN = 768, nT = 12, nM = nN * nT, nH = 64;
constexpr float SCALE = 0.125f;
constexpr float LNEPS = 1e-6f;

// ---------------- bf16 helpers ----------------
__device__ inline u16 f2b(float f) {
    union { float f; unsigned u; } v; v.f = f;
    unsigned r = v.u + 0x7FFFu + ((v.u >> 16) & 1u);
    return (u16)(r >> 16);
}
__device__ inline float b2f(u16 h) {
    union { unsigned u; float f; } v; v.u = ((unsigned)h) << 16;
    return v.f;
}
__device__ inline uint2 packb4(float a, float b, float c, float d) {
    uint2 r;
    r.x = (unsigned)f2b(a) | ((unsigned)f2b(b) << 16);
    r.y = (unsigned)f2b(c) | ((unsigned)f2b(d) << 16);
    return r;
}
__device__ inline f32x4 mfma16(bf16x8 a, bf16x8 b, f32x4 c) {
    return __builtin_amdgcn_mfma_f32_16x16x32_bf16(a, b, c, 0, 0, 0);
}

// Stage a 64x64 bf16 tile (row stride ld elements) into LDS [64][72].
__device__ inline void stage64(const u16* __restrict__ g, int ld, u16* lds, int tid) {
#pragma unroll
    for (int r = 0; r < 2; ++r) {
        int c = tid + r * 256;
        int row = c >> 3, kc = (c & 7) * 8;
        *(uint4*)&lds[row * 72 + kc] = *(const uint4*)&g[(size_t)row * ld + kc];
    }
}

// One 64-wide K-chunk of MFMA compute. acc[2][2] over (o-sub, m-sub) 16x16 tiles.
// Output element: A-row = wo + oi*16 + quad*4 + rr (contiguous rr),
//                 B-row = wm + mj*16 + r (lane-fast r).
__device__ inline void mfma_block(const u16* As, const u16* Bs, f32x4 acc[2][2],
                                  int wo, int wm, int quad, int r) {
#pragma unroll
    for (int ks = 0; ks < 64; ks += 32) {
        bf16x8 a0 = *(const bf16x8*)&As[(wo + r) * 72 + ks + quad * 8];
        bf16x8 a1 = *(const bf16x8*)&As[(wo + 16 + r) * 72 + ks + quad * 8];
        bf16x8 b0 = *(const bf16x8*)&Bs[(wm + r) * 72 + ks + quad * 8];
        bf16x8 b1 = *(const bf16x8*)&Bs[(wm + 16 + r) * 72 + ks + quad * 8];
        acc[0][0] = mfma16(a0, b0, acc[0][0]);
        acc[0][1] = mfma16(a0, b1, acc[0][1]);
        acc[1][0] = mfma16(a1, b0, acc[1][0]);
        acc[1][1] = mfma16(a1, b1, acc[1][1]);
    }
}

// ---------------- weight conversion (fp32 -> bf16, with q/k transposes) ------
// Layout in WB (u16): wq@0 wk@16384 wtq@32768 wtk@49152 wv@65536 wfcv@81920
//                     wproj@114688 wf1@147456 wf2@409600, total 540672
__global__ __launch_bounds__(256) void cvt_w(const float* __restrict__ Wnq,
                                             const float* __restrict__ Wnk,
                                             const float* __restrict__ Wtq,
                                             const float* __restrict__ Wtk,
                                             const float* __restrict__ vw,
                                             const float* __restrict__ fcvw,
                                             const float* __restrict__ projw,
                                             const float* __restrict__ w1,
                                             const float* __restrict__ w2,
                                             u16* __restrict__ WB) {
    int i = blockIdx.x * 256 + threadIdx.x;
    float v;
    if (i < 65536) {
        int seg = i >> 14, j = i & 16383;
        int o = j >> 8, k = j & 255;
        const float* src = seg == 0 ? Wnq : seg == 1 ? Wnk : seg == 2 ? Wtq : Wtk;
        v = src[k * 64 + o];                       // [c][h] -> [h][c]
    } else if (i < 81920)  v = vw[i - 65536];
    else if (i < 114688)   v = fcvw[i - 81920];
    else if (i < 147456)   v = projw[i - 114688];
    else if (i < 409600)   v = w1[i - 147456];
    else                   v = w2[i - 409600];
    WB[i] = f2b(v);
}

// ---------------- LayerNorm (channels-first fp32 in, channels-last bf16 out) --
__global__ __launch_bounds__(256) void ln_cl(const float* __restrict__ X,
                                             const float* __restrict__ w,
                                             const float* __restrict__ bias,
                                             u16* __restrict__ Y) {
    int tid = threadIdx.x;
    int lane = tid & 63, cg = tid >> 6;
    int m0 = blockIdx.x * 64, b = blockIdx.y;
    size_t base = (size_t)b * nC * nM + m0 + lane;
    float s = 0.f, ss = 0.f;
#pragma unroll 4
    for (int k = 0; k < 64; ++k) {
        float v = X[base + (size_t)(cg * 64 + k) * nM];
        s += v; ss += v * v;
    }
    __shared__ float rs[4][64], rss[4][64], mu_s[64], rstd_s[64];
    __shared__ u16 Lo[64][264];
    rs[cg][lane] = s; rss[cg][lane] = ss;
    __syncthreads();
    if (tid < 64) {
        float t1 = rs[0][lane] + rs[1][lane] + rs[2][lane] + rs[3][lane];
        float t2 = rss[0][lane] + rss[1][lane] + rss[2][lane] + rss[3][lane];
        float mu = t1 * (1.f / nC);
        float var = t2 * (1.f / nC) - mu * mu;
        mu_s[lane] = mu;
        rstd_s[lane] = rsqrtf(var + LNEPS);
    }
    __syncthreads();
    float mu = mu_s[lane], rstd = rstd_s[lane];
#pragma unroll 8
    for (int k = 0; k < 64; k += 2) {
        int c = cg * 64 + k;
        float v0 = (X[base + (size_t)c * nM] - mu) * rstd * w[c] + bias[c];
        float v1 = (X[base + (size_t)(c + 1) * nM] - mu) * rstd * w[c + 1] + bias[c + 1];
        *(unsigned*)&Lo[lane][c] = (unsigned)f2b(v0) | ((unsigned)f2b(v1) << 16);
    }
    __syncthreads();
#pragma unroll
    for (int r = 0; r < 8; ++r) {
        int c = tid + r * 256;
        int mm = c >> 5, ch = (c & 31) * 8;
        *(uint4*)&Y[((size_t)b * nM + m0 + mm) * 256 + ch] = *(uint4*)&Lo[mm][ch];
    }
}

// ---------------- generic projection GEMM (X channels-last, K=256) ----------
// o-tile on blockIdx.x (fast) so o-siblings of one m-tile dispatch together
// and share the staged activation tile via L2.
// LAYOUT 0: OUT[(b*12+t)][n][COUT] (nq/nk)   1: OUT[b][m][COUT] (tq/tk/fcv)
//        2: OUT[(b*12+t)][o][n] (v1)
template <int COUT, int LAYOUT>
__global__ __launch_bounds__(256) void gemm_proj(const u16* __restrict__ X,
                                                 const u16* __restrict__ W,
                                                 const float* __restrict__ bias,
                                                 u16* __restrict__ OUT) {
    __shared__ u16 As[64 * 72], Bs[64 * 72];
    int tid = threadIdx.x;
    int m0 = blockIdx.y * 64, o0 = blockIdx.x * 64, b = blockIdx.z;
    int lane = tid & 63, wid = tid >> 6;
    int wo = (wid & 1) * 32, wm = (wid >> 1) * 32;
    int quad = lane >> 4, r = lane & 15;
    const u16* Ag = W + (size_t)o0 * 256;
    const u16* Bg = X + ((size_t)b * nM + m0) * 256;
    f32x4 acc[2][2] = {};
    for (int k0 = 0; k0 < 256; k0 += 64) {
        __syncthreads();
        stage64(Ag + k0, 256, As, tid);
        stage64(Bg + k0, 256, Bs, tid);
        __syncthreads();
        mfma_block(As, Bs, acc, wo, wm, quad, r);
    }
#pragma unroll
    for (int oi = 0; oi < 2; ++oi)
#pragma unroll
        for (int mj = 0; mj < 2; ++mj) {
            int o = o0 + wo + oi * 16 + quad * 4;
            int m = m0 + wm + mj * 16 + r;
            f32x4 a = acc[oi][mj];
            float v0 = a[0] + bias[o], v1 = a[1] + bias[o + 1];
            float v2 = a[2] + bias[o + 2], v3 = a[3] + bias[o + 3];
            if (LAYOUT == 1) {
                *(uint2*)&OUT[((size_t)b * nM + m) * COUT + o] = packb4(v0, v1, v2, v3);
            } else if (LAYOUT == 0) {
                int n = m / 12, t = m - n * 12;
                *(uint2*)&OUT[((size_t)(b * 12 + t) * nN + n) * COUT + o] =
                    packb4(v0, v1, v2, v3);
            } else {
                int n = m / 12, t = m - n * 12;
                size_t bt = (size_t)(b * 12 + t) * 64;
                OUT[(bt + o) * nN + n]     = f2b(v0);
                OUT[(bt + o + 1) * nN + n] = f2b(v1);
                OUT[(bt + o + 2) * nN + n] = f2b(v2);
                OUT[(bt + o + 3) * nN + n] = f2b(v3);
            }
        }
}

// ---------------- node softmax row-sums (no score store; writes reciprocals) -
__global__ __launch_bounds__(256) void rowsum_k(const u16* __restrict__ NQ,
                                                const u16* __restrict__ NK,
                                                const float* __restrict__ Bn,
                                                float* __restrict__ RINV) {
    __shared__ u16 Qt[64 * 72], Kt[64 * 72];
    __shared__ float lsum[64];
    int tid = threadIdx.x;
    int i0 = blockIdx.x * 64, bt = blockIdx.y;
    int lane = tid & 63, wid = tid >> 6;
    int wo = (wid & 1) * 32, wm = (wid >> 1) * 32;
    int quad = lane >> 4, r = lane & 15;
    if (tid < 64) lsum[tid] = 0.f;
    stage64(NQ + ((size_t)bt * nN + i0) * 64, 64, Qt, tid);
    float rsm[2] = {0.f, 0.f};   // per mj (row i = wm + mj*16 + r)
    for (int j0 = 0; j0 < nN; j0 += 64) {
        __syncthreads();
        stage64(NK + ((size_t)bt * nN + j0) * 64, 64, Kt, tid);
        __syncthreads();
        // A = K (rows j), B = Q (rows i): acc[oi][mj][rr] at
        //   j = j0 + wo + oi*16 + quad*4 + rr,  i = i0 + wm + mj*16 + r
        f32x4 acc[2][2] = {};
        mfma_block(Kt, Qt, acc, wo, wm, quad, r);
#pragma unroll
        for (int mj = 0; mj < 2; ++mj) {
            int i_ = i0 + wm + mj * 16 + r;
#pragma unroll
            for (int oi = 0; oi < 2; ++oi) {
                int j_ = j0 + wo + oi * 16 + quad * 4;
                f32x4 b4 = *(const f32x4*)&Bn[(size_t)i_ * nN + j_];
#pragma unroll
                for (int rr = 0; rr < 4; ++rr)
                    rsm[mj] += expf(acc[oi][mj][rr] * SCALE + b4[rr]);
            }
        }
    }
    // reduce over the 4 quads (they cover different j), rows live on (mj, r)
#pragma unroll
    for (int mj = 0; mj < 2; ++mj) {
        rsm[mj] += __shfl_xor(rsm[mj], 16);
        rsm[mj] += __shfl_xor(rsm[mj], 32);
    }
    if (quad == 0) {
#pragma unroll
        for (int mj = 0; mj < 2; ++mj)
            atomicAdd(&lsum[wm + mj * 16 + r], rsm[mj]);   // combine wo=0/32 waves
    }
    __syncthreads();
    if (tid < 64) RINV[(size_t)bt * nN + i0 + tid] = 1.f / lsum[tid];
}

// ---------------- fused node attention + aggregation -------------------------
// Per (w-tile, bt): K w-tile resident in LDS. Loop v-tiles: recompute score
// tile via MFMA with A=Q, B=K so the lane-fast index r walks the w axis ->
// adj/Bn reads are coalesced 64B segments, and the Pt deposit is one packed
// uint2 per (oi,mj). Scores are bitwise identical to rowsum_k's.
__global__ __launch_bounds__(256) void node_agg_fused(const u16* __restrict__ NQ,
                                                      const u16* __restrict__ NK,
                                                      const u16* __restrict__ V1N,
                                                      const float* __restrict__ RINV,
                                                      const float* __restrict__ adj,
                                                      const float* __restrict__ Bn,
                                                      u16* __restrict__ HB) {
    __shared__ u16 Kt[64 * 72], Qt[64 * 72], Vt[64 * 72], Pt[64 * 72];
    __shared__ float rinv_s[64];
    int tid = threadIdx.x;
    int w0 = blockIdx.x * 64, bt = blockIdx.y;
    int b = bt / 12, l = bt - b * 12;
    int lane = tid & 63, wid = tid >> 6;
    int wo = (wid & 1) * 32, wm = (wid >> 1) * 32;
    int quad = lane >> 4, r = lane & 15;
    stage64(NK + ((size_t)bt * nN + w0) * 64, 64, Kt, tid);
    f32x4 acc2[2][2] = {};
    for (int v0 = 0; v0 < nN; v0 += 64) {
        __syncthreads();   // prev-iter mfma reads of Qt/Vt/Pt done; Kt visible
        stage64(NQ + ((size_t)bt * nN + v0) * 64, 64, Qt, tid);
        stage64(V1N + (size_t)bt * 64 * nN + v0, nN, Vt, tid);
        if (tid < 64) rinv_s[tid] = RINV[(size_t)bt * nN + v0 + tid];
        __syncthreads();
        // scores: A = Q (rows v), B = K (rows w):
        //   v = v0 + wo + oi*16 + quad*4 + rr (contiguous rr)
        //   w = w0 + wm + mj*16 + r           (lane-fast -> coalesced adj/Bn)
        f32x4 acc1[2][2] = {};
        mfma_block(Qt, Kt, acc1, wo, wm, quad, r);
#pragma unroll
        for (int oi = 0; oi < 2; ++oi)
#pragma unroll
            for (int mj = 0; mj < 2; ++mj) {
                int vl = wo + oi * 16 + quad * 4;
                int wl = wm + mj * 16 + r;
                const float* ap = adj + ((size_t)bt * nN + v0 + vl) * nN + w0 + wl;
                const float* bp = Bn + (size_t)(v0 + vl) * nN + w0 + wl;
                float pv[4];
#pragma unroll
                for (int rr = 0; rr < 4; ++rr) {
                    float e = expf(acc1[oi][mj][rr] * SCALE + bp[(size_t)rr * nN]);
                    pv[rr] = e * ap[(size_t)rr * nN] * rinv_s[vl + rr];
                }
                *(uint2*)&Pt[wl * 72 + vl] = packb4(pv[0], pv[1], pv[2], pv[3]);
            }
        __syncthreads();
        // aggregate: A = v1 (rows c), B = P (rows w), k = v
        mfma_block(Vt, Pt, acc2, wo, wm, quad, r);
    }
#pragma unroll
    for (int oi = 0; oi < 2; ++oi)
#pragma unroll
        for (int mj = 0; mj < 2; ++mj) {
            int c = wo + oi * 16 + quad * 4;
            int w = w0 + wm + mj * 16 + r;
            f32x4 a = acc2[oi][mj];
            *(uint2*)&HB[((size_t)b * nM + w * 12 + l) * 128 + 64 + c] =
                packb4(a[0], a[1], a[2], a[3]);
        }
}

// ---------------- time attention (tiny) -------------------------------------
__global__ __launch_bounds__(192) void time_attn(const u16* __restrict__ TQ,
                                                 const u16* __restrict__ TK,
                                                 const float* __restrict__ Bt,
                                                 float* __restrict__ AT) {
    int bn = blockIdx.x;  // b*768 + n
    __shared__ float tqs[nT * 64], tks[nT * 64], ss[nT * nT];
    __shared__ float inv_s[nT], max_s[nT];
    int tid = threadIdx.x;
    size_t base = (size_t)bn * nT * 64;
#pragma unroll
    for (int r = 0; r < 4; ++r) {
        int idx = tid + r * 192;
        tqs[idx] = b2f(TQ[base + idx]);
        tks[idx] = b2f(TK[base + idx]);
    }
    __syncthreads();
    if (tid < 144) {
        int i = tid / 12, j = tid % 12;
        float s = 0.f;
#pragma unroll
        for (int h = 0; h < 64; ++h) s += tqs[i * 64 + h] * tks[j * 64 + h];
        ss[tid] = s * SCALE + Bt[i * 12 + j];
    }
    __syncthreads();
    if (tid < 12) {
        float mx = -1e30f;
        for (int j = 0; j < 12; ++j) mx = fmaxf(mx, ss[tid * 12 + j]);
        float sm = 0.f;
        for (int j = 0; j < 12; ++j) sm += expf(ss[tid * 12 + j] - mx);
        max_s[tid] = mx; inv_s[tid] = 1.f / sm;
    }
    __syncthreads();
    if (tid < 144) {
        int i = tid / 12;
        AT[(size_t)bn * 144 + tid] = expf(ss[tid] - max_s[i]) * inv_s[i];
    }
}

// ---------------- time aggregation ------------------------------------------
__global__ __launch_bounds__(256) void time_agg_k(const u16* __restrict__ V1N,
                                                  const float* __restrict__ AT,
                                                  u16* __restrict__ HB) {
    int tid = threadIdx.x;
    int lane = tid & 63, cg = tid >> 6;
    int n = blockIdx.x * 64 + lane;
    int b = blockIdx.y;
    size_t bn = (size_t)b * nN + n;
#pragma unroll 2
    for (int cc = 0; cc < 16; ++cc) {
        int c = cg * 16 + cc;
        float acc[12] = {};
        for (int v = 0; v < 12; ++v) {
            float val = b2f(V1N[((size_t)(b * 12 + v) * 64 + c) * nN + n]);
            const float4* at4 = (const float4*)(AT + bn * 144 + v * 12);
            float4 a0 = at4[0], a1 = at4[1], a2 = at4[2];
            acc[0] += val * a0.x;  acc[1] += val * a0.y;
            acc[2] += val * a0.z;  acc[3] += val * a0.w;
            acc[4] += val * a1.x;  acc[5] += val * a1.y;
            acc[6] += val * a1.z;  acc[7] += val * a1.w;
            acc[8] += val * a2.x;  acc[9] += val * a2.y;
            acc[10] += val * a2.z; acc[11] += val * a2.w;
        }
#pragma unroll
        for (int t = 0; t < 12; ++t)
            HB[((size_t)b * nM + n * 12 + t) * 128 + c] = f2b(acc[t]);
    }
}

// ---------------- proj GEMM on (h .* vg), channels-first fp32 out + residual -
__global__ __launch_bounds__(256) void prodproj_k(const u16* __restrict__ HB,
                                                  const u16* __restrict__ VG,
                                                  const u16* __restrict__ W,
                                                  const float* __restrict__ bias,
                                                  const float* __restrict__ RES,
                                                  float* __restrict__ OUT) {
    __shared__ u16 As[64 * 72], Bs[64 * 72];
    int tid = threadIdx.x;
    int m0 = blockIdx.y * 64, o0 = blockIdx.x * 64, b = blockIdx.z;
    int lane = tid & 63, wid = tid >> 6;
    int wo = (wid & 1) * 32, wm = (wid >> 1) * 32;
    int quad = lane >> 4, r = lane & 15;
    f32x4 acc[2][2] = {};
    for (int k0 = 0; k0 < 128; k0 += 64) {
        __syncthreads();
        stage64(W + (size_t)o0 * 128 + k0, 128, As, tid);
#pragma unroll
        for (int rr = 0; rr < 2; ++rr) {
            int c = tid + rr * 256;
            int row = c >> 3, kc = (c & 7) * 8;
            size_t gi = ((size_t)b * nM + m0 + row) * 128 + k0 + kc;
            uint4 hv = *(const uint4*)&HB[gi];
            uint4 vv = *(const uint4*)&VG[gi];
            u16* hs = (u16*)&hv; u16* vs = (u16*)&vv;
            union { uint4 q; u16 s[8]; } ov;
#pragma unroll
            for (int q2 = 0; q2 < 8; ++q2) ov.s[q2] = f2b(b2f(hs[q2]) * b2f(vs[q2]));
            *(uint4*)&Bs[row * 72 + kc] = ov.q;
        }
        __syncthreads();
        mfma_block(As, Bs, acc, wo, wm, quad, r);
    }
#pragma unroll
    for (int oi = 0; oi < 2; ++oi)
#pragma unroll
        for (int mj = 0; mj < 2; ++mj) {
            int o = o0 + wo + oi * 16 + quad * 4;
            int m = m0 + wm + mj * 16 + r;
            f32x4 a = acc[oi][mj];
#pragma unroll
            for (int rr = 0; rr < 4; ++rr) {
                size_t idx = ((size_t)(b * nC + o + rr)) * nM + m;
                OUT[idx] = a[rr] + bias[o + rr] + RES[idx];
            }
        }
}

// ---------------- FFN1 gated (a * gelu(g)) -> bf16 channels-last ------------
__global__ __launch_bounds__(256) void ffn1_k(const u16* __restrict__ X,
                                              const u16* __restrict__ W1,
                                              const float* __restrict__ B1,
                                              u16* __restrict__ G1) {
    __shared__ u16 As[64 * 72], Gs[64 * 72], Bs[64 * 72];
    int tid = threadIdx.x;
    int m0 = blockIdx.y * 64, o0 = blockIdx.x * 64, b = blockIdx.z;
    int lane = tid & 63, wid = tid >> 6;
    int wo = (wid & 1) * 32, wm = (wid >> 1) * 32;
    int quad = lane >> 4, r = lane & 15;
    f32x4 acca[2][2] = {}, accg[2][2] = {};
    for (int k0 = 0; k0 < 256; k0 += 64) {
        __syncthreads();
        stage64(W1 + (size_t)o0 * 256 + k0, 256, As, tid);
        stage64(W1 + (size_t)(512 + o0) * 256 + k0, 256, Gs, tid);
        stage64(X + ((size_t)b * nM + m0) * 256 + k0, 256, Bs, tid);
        __syncthreads();
#pragma unroll
        for (int ks = 0; ks < 64; ks += 32) {
            bf16x8 a0 = *(const bf16x8*)&As[(wo + r) * 72 + ks + quad * 8];
            bf16x8 a1 = *(const bf16x8*)&As[(wo + 16 + r) * 72 + ks + quad * 8];
            bf16x8 g0 = *(const bf16x8*)&Gs[(wo + r) * 72 + ks + quad * 8];
            bf16x8 g1 = *(const bf16x8*)&Gs[(wo + 16 + r) * 72 + ks + quad * 8];
            bf16x8 b0 = *(const bf16x8*)&Bs[(wm + r) * 72 + ks + quad * 8];
            bf16x8 b1 = *(const bf16x8*)&Bs[(wm + 16 + r) * 72 + ks + quad * 8];
            acca[0][0] = mfma16(a0, b0, acca[0][0]);
            acca[0][1] = mfma16(a0, b1, acca[0][1]);
            acca[1][0] = mfma16(a1, b0, acca[1][0]);
            acca[1][1] = mfma16(a1, b1, acca[1][1]);
            accg[0][0] = mfma16(g0, b0, accg[0][0]);
            accg[0][1] = mfma16(g0, b1, accg[0][1]);
            accg[1][0] = mfma16(g1, b0, accg[1][0]);
            accg[1][1] = mfma16(g1, b1, accg[1][1]);
        }
    }
#pragma unroll
    for (int oi = 0; oi < 2; ++oi)
#pragma unroll
        for (int mj = 0; mj < 2; ++mj) {
            int o = o0 + wo + oi * 16 + quad * 4;
            int m = m0 + wm + mj * 16 + r;
            float vals[4];
#pragma unroll
            for (int rr = 0; rr < 4; ++rr) {
                float aa = acca[oi][mj][rr] + B1[o + rr];
                float gg = accg[oi][mj][rr] + B1[512 + o + rr];
                float gl = 0.5f * gg * (1.f + erff(gg * 0.70710678118654752f));
                vals[rr] = aa * gl;
            }
            *(uint2*)&G1[((size_t)b * nM + m) * 512 + o] =
                packb4(vals[0], vals[1], vals[2], vals[3]);
        }
}

// ---------------- FFN2: channels-first fp32 out + residual ------------------
__global__ __launch_bounds__(256) void ffn2_k(const u16* __restrict__ G1,
                                              const u16* __restrict__ W2,
                                              const float* __restrict__ B2,
                                              const float* __restrict__ RES,
                                              float* __restrict__ OUT) {
    __shared__ u16 As[64 * 72], Bs[64 * 72];
    int tid = threadIdx.x;
    int m0 = blockIdx.y * 64, o0 = blockIdx.x * 64, b = blockIdx.z;
    int lane = tid & 63, wid = tid >> 6;
    int wo = (wid & 1) * 32, wm = (wid >> 1) * 32;
    int quad = lane >> 4, r = lane & 15;
    f32x4 acc[2][2] = {};
    for (int k0 = 0; k0 < 512; k0 += 64) {
        __syncthreads();
        stage64(W2 + (size_t)o0 * 512 + k0, 512, As, tid);
        stage64(G1 + ((size_t)b * nM + m0) * 512 + k0, 512, Bs, tid);
        __syncthreads();
        mfma_block(As, Bs, acc, wo, wm, quad, r);
    }
#pragma unroll
    for (int oi = 0; oi < 2; ++oi)
#pragma unroll
        for (int mj = 0; mj < 2; ++mj) {
            int o = o0 + wo + oi * 16 + quad * 4;
            int m = m0 + wm + mj * 16 + r;
            f32x4 a = acc[oi][mj];
#pragma unroll
            for (int rr = 0; rr < 4; ++rr) {
                size_t idx = ((size_t)(b * nC + o + rr)) * nM + m;
                OUT[idx] = a[rr] + B2[o + rr] + RES[idx];
            }
        }
}

// ---------------------------------------------------------------------------
extern "C" void kernel_launch(void* const* d_in, const int* in_sizes, int n_in,
                              void* d_out, int out_size, void* d_ws, size_t ws_size,
                              hipStream_t stream) {
    const float* x      = (const float*)d_in[0];
    const float* adj    = (const float*)d_in[4];
    const float* ln1w   = (const float*)d_in[5];
    const float* ln1b   = (const float*)d_in[6];
    const float* ln2w   = (const float*)d_in[7];
    const float* ln2b   = (const float*)d_in[8];
    const float* Wnq    = (const float*)d_in[9];
    const float* bnq    = (const float*)d_in[10];
    const float* Wnk    = (const float*)d_in[11];
    const float* bnk    = (const float*)d_in[12];
    const float* Wtq    = (const float*)d_in[13];
    const float* btq    = (const float*)d_in[14];
    const float* Wtk    = (const float*)d_in[15];
    const float* btk    = (const float*)d_in[16];
    const float* Bn     = (const float*)d_in[17];
    const float* Bt     = (const float*)d_in[18];
    const float* v_w    = (const float*)d_in[19];
    const float* v_b    = (const float*)d_in[20];
    const float* fcv_w  = (const float*)d_in[21];
    const float* fcv_b  = (const float*)d_in[22];
    const float* proj_w = (const float*)d_in[23];
    const float* proj_b = (const float*)d_in[24];
    const float* w1     = (const float*)d_in[25];
    const float* b1     = (const float*)d_in[26];
    const float* w2     = (const float*)d_in[27];
    const float* b2     = (const float*)d_in[28];
    float* out = (float*)d_out;

    char* p = (char*)d_ws;
    auto alloc = [&](size_t bytes) { char* q = p; p += (bytes + 255) & ~(size_t)255; return q; };
    u16*   x1cl   = (u16*)alloc(37748736);   // [B][M][256] bf16
    u16*   nqb    = (u16*)alloc(9437184);    // [BT][N][64] / [B][M][64]
    u16*   nkb    = (u16*)alloc(9437184);
    u16*   v1n    = (u16*)alloc(9437184);    // [BT][64][N]
    float* atT    = (float*)alloc(3538944);  // [B][N][12][12]
    u16*   hb     = (u16*)alloc(18874368);   // [B][M][128]
    u16*   vg     = (u16*)alloc(18874368);   // [B][M][128]
    float* rinv   = (float*)alloc(294912);   // [BT][N] reciprocal row-sums
    u16*   WB     = (u16*)alloc(1081344);    // bf16 weights
    float* xr     = (float*)alloc(75497472); // [B][256][M] fp32
    u16*   x2cl   = (u16*)alloc(37748736);   // [B][M][256] bf16
    u16*   g1     = (u16*)alloc(75497472);   // [B][M][512] bf16

    dim3 blk(256);
    cvt_w<<<dim3(2112), blk, 0, stream>>>(Wnq, Wnk, Wtq, Wtk, v_w, fcv_w, proj_w,
                                          w1, w2, WB);
    ln_cl<<<dim3(144, nB), blk, 0, stream>>>(x, ln1w, ln1b, x1cl);
    // --- node attention path (nqb/nkb hold node q/k until node_agg_fused) ---
    gemm_proj<64, 0><<<dim3(1, 144, nB), blk, 0, stream>>>(x1cl, WB + 0, bnq, nqb);
    gemm_proj<64, 0><<<dim3(1, 144, nB), blk, 0, stream>>>(x1cl, WB + 16384, bnk, nkb);
    rowsum_k<<<dim3(12, nB * nT), blk, 0, stream>>>(nqb, nkb, Bn, rinv);
    gemm_proj<64, 2><<<dim3(1, 144, nB), blk, 0, stream>>>(x1cl, WB + 65536, v_b, v1n);
    node_agg_fused<<<dim3(12, nB * nT), blk, 0, stream>>>(nqb, nkb, v1n, rinv,
                                                          adj, Bn, hb);
    // --- time attention path (reuses nqb/nkb) ---
    gemm_proj<64, 1><<<dim3(1, 144, nB), blk, 0, stream>>>(x1cl, WB + 32768, btq, nqb);
    gemm_proj<64, 1><<<dim3(1, 144, nB), blk, 0, stream>>>(x1cl, WB + 49152, btk, nkb);
    time_attn<<<dim3(nB * nN), dim3(192), 0, stream>>>(nqb, nkb, Bt, atT);
    time_agg_k<<<dim3(12, nB), blk, 0, stream>>>(v1n, atT, hb);
    // --- gate, proj, FFN ---
    gemm_proj<128, 1><<<dim3(2, 144, nB), blk, 0, stream>>>(x1cl, WB + 81920, fcv_b, vg);
    prodproj_k<<<dim3(4, 144, nB), blk, 0, stream>>>(hb, vg, WB + 114688, proj_b, x, xr);
    ln_cl<<<dim3(144, nB), blk, 0, stream>>>(xr, ln2w, ln2b, x2cl);
    ffn1_k<<<dim3(8, 144, nB), blk, 0, stream>>>(x2cl, WB + 147456, b1, g1);
    ffn2_k<<<dim3(4, 144, nB), blk, 0, stream>>>(g1, WB + 409600, b2, xr, out);
}

// Round 3
// 926.006 us; speedup vs baseline: 1.0907x; 1.0907x over previous
//
#include <hip/hip_runtime.h>
#include <cstddef>

typedef unsigned short u16;
typedef __attribute__((ext_vector_type(8))) short bf16x8;
typedef __attribute__((ext_vector_type(4))) float f32x4;

constexpr int nB = 8, nC = 256, nN = 768, nT = 12, nM = nN * nT, nH = 64;
constexpr float SCALE = 0.125f;
constexpr float LNEPS = 1e-6f;

// ---------------- bf16 helpers ----------------
__device__ inline u16 f2b(float f) {
    union { float f; unsigned u; } v; v.f = f;
    unsigned r = v.u + 0x7FFFu + ((v.u >> 16) & 1u);
    return (u16)(r >> 16);
}
__device__ inline float b2f(u16 h) {
    union { unsigned u; float f; } v; v.u = ((unsigned)h) << 16;
    return v.f;
}
__device__ inline uint2 packb4(float a, float b, float c, float d) {
    uint2 r;
    r.x = (unsigned)f2b(a) | ((unsigned)f2b(b) << 16);
    r.y = (unsigned)f2b(c) | ((unsigned)f2b(d) << 16);
    return r;
}
__device__ inline f32x4 mfma16(bf16x8 a, bf16x8 b, f32x4 c) {
    return __builtin_amdgcn_mfma_f32_16x16x32_bf16(a, b, c, 0, 0, 0);
}

// Stage a 64x64 bf16 tile (row stride ld elements) into LDS [64][72].
__device__ inline void stage64(const u16* __restrict__ g, int ld, u16* lds, int tid) {
#pragma unroll
    for (int r = 0; r < 2; ++r) {
        int c = tid + r * 256;
        int row = c >> 3, kc = (c & 7) * 8;
        *(uint4*)&lds[row * 72 + kc] = *(const uint4*)&g[(size_t)row * ld + kc];
    }
}

// One 64-wide K-chunk of MFMA compute. acc[2][2] over (o-sub, m-sub) 16x16 tiles.
// Output element: A-row = wo + oi*16 + quad*4 + rr (contiguous rr),
//                 B-row = wm + mj*16 + r (lane-fast r).
__device__ inline void mfma_block(const u16* As, const u16* Bs, f32x4 acc[2][2],
                                  int wo, int wm, int quad, int r) {
#pragma unroll
    for (int ks = 0; ks < 64; ks += 32) {
        bf16x8 a0 = *(const bf16x8*)&As[(wo + r) * 72 + ks + quad * 8];
        bf16x8 a1 = *(const bf16x8*)&As[(wo + 16 + r) * 72 + ks + quad * 8];
        bf16x8 b0 = *(const bf16x8*)&Bs[(wm + r) * 72 + ks + quad * 8];
        bf16x8 b1 = *(const bf16x8*)&Bs[(wm + 16 + r) * 72 + ks + quad * 8];
        acc[0][0] = mfma16(a0, b0, acc[0][0]);
        acc[0][1] = mfma16(a0, b1, acc[0][1]);
        acc[1][0] = mfma16(a1, b0, acc[1][0]);
        acc[1][1] = mfma16(a1, b1, acc[1][1]);
    }
}

// ---------------- weight conversion (fp32 -> bf16, with q/k transposes) ------
// Layout in WB (u16): wq@0 wk@16384 wtq@32768 wtk@49152 wv@65536 wfcv@81920
//                     wproj@114688 wf1@147456 wf2@409600, total 540672
__global__ __launch_bounds__(256) void cvt_w(const float* __restrict__ Wnq,
                                             const float* __restrict__ Wnk,
                                             const float* __restrict__ Wtq,
                                             const float* __restrict__ Wtk,
                                             const float* __restrict__ vw,
                                             const float* __restrict__ fcvw,
                                             const float* __restrict__ projw,
                                             const float* __restrict__ w1,
                                             const float* __restrict__ w2,
                                             u16* __restrict__ WB) {
    int i = blockIdx.x * 256 + threadIdx.x;
    float v;
    if (i < 65536) {
        int seg = i >> 14, j = i & 16383;
        int o = j >> 8, k = j & 255;
        const float* src = seg == 0 ? Wnq : seg == 1 ? Wnk : seg == 2 ? Wtq : Wtk;
        v = src[k * 64 + o];                       // [c][h] -> [h][c]
    } else if (i < 81920)  v = vw[i - 65536];
    else if (i < 114688)   v = fcvw[i - 81920];
    else if (i < 147456)   v = projw[i - 114688];
    else if (i < 409600)   v = w1[i - 147456];
    else                   v = w2[i - 409600];
    WB[i] = f2b(v);
}

// ---------------- LayerNorm (channels-first fp32 in, channels-last bf16 out) --
__global__ __launch_bounds__(256) void ln_cl(const float* __restrict__ X,
                                             const float* __restrict__ w,
                                             const float* __restrict__ bias,
                                             u16* __restrict__ Y) {
    int tid = threadIdx.x;
    int lane = tid & 63, cg = tid >> 6;
    int m0 = blockIdx.x * 64, b = blockIdx.y;
    size_t base = (size_t)b * nC * nM + m0 + lane;
    float s = 0.f, ss = 0.f;
#pragma unroll 4
    for (int k = 0; k < 64; ++k) {
        float v = X[base + (size_t)(cg * 64 + k) * nM];
        s += v; ss += v * v;
    }
    __shared__ float rs[4][64], rss[4][64], mu_s[64], rstd_s[64];
    __shared__ u16 Lo[64][264];
    rs[cg][lane] = s; rss[cg][lane] = ss;
    __syncthreads();
    if (tid < 64) {
        float t1 = rs[0][lane] + rs[1][lane] + rs[2][lane] + rs[3][lane];
        float t2 = rss[0][lane] + rss[1][lane] + rss[2][lane] + rss[3][lane];
        float mu = t1 * (1.f / nC);
        float var = t2 * (1.f / nC) - mu * mu;
        mu_s[lane] = mu;
        rstd_s[lane] = rsqrtf(var + LNEPS);
    }
    __syncthreads();
    float mu = mu_s[lane], rstd = rstd_s[lane];
#pragma unroll 8
    for (int k = 0; k < 64; k += 2) {
        int c = cg * 64 + k;
        float v0 = (X[base + (size_t)c * nM] - mu) * rstd * w[c] + bias[c];
        float v1 = (X[base + (size_t)(c + 1) * nM] - mu) * rstd * w[c + 1] + bias[c + 1];
        *(unsigned*)&Lo[lane][c] = (unsigned)f2b(v0) | ((unsigned)f2b(v1) << 16);
    }
    __syncthreads();
#pragma unroll
    for (int r = 0; r < 8; ++r) {
        int c = tid + r * 256;
        int mm = c >> 5, ch = (c & 31) * 8;
        *(uint4*)&Y[((size_t)b * nM + m0 + mm) * 256 + ch] = *(uint4*)&Lo[mm][ch];
    }
}

// ---------------- generic projection GEMM (X channels-last, K=256) ----------
// LAYOUT 0: OUT[(b*12+t)][n][COUT] (nq/nk)   1: OUT[b][m][COUT] (tq/tk/fcv)
//        2: OUT[(b*12+t)][o][n] (v1)
template <int COUT, int LAYOUT>
__global__ __launch_bounds__(256) void gemm_proj(const u16* __restrict__ X,
                                                 const u16* __restrict__ W,
                                                 const float* __restrict__ bias,
                                                 u16* __restrict__ OUT) {
    __shared__ u16 As[64 * 72], Bs[64 * 72];
    int tid = threadIdx.x;
    int m0 = blockIdx.x * 64, o0 = blockIdx.y * 64, b = blockIdx.z;
    int lane = tid & 63, wid = tid >> 6;
    int wo = (wid & 1) * 32, wm = (wid >> 1) * 32;
    int quad = lane >> 4, r = lane & 15;
    const u16* Ag = W + (size_t)o0 * 256;
    const u16* Bg = X + ((size_t)b * nM + m0) * 256;
    f32x4 acc[2][2] = {};
    for (int k0 = 0; k0 < 256; k0 += 64) {
        __syncthreads();
        stage64(Ag + k0, 256, As, tid);
        stage64(Bg + k0, 256, Bs, tid);
        __syncthreads();
        mfma_block(As, Bs, acc, wo, wm, quad, r);
    }
#pragma unroll
    for (int oi = 0; oi < 2; ++oi)
#pragma unroll
        for (int mj = 0; mj < 2; ++mj) {
            int o = o0 + wo + oi * 16 + quad * 4;
            int m = m0 + wm + mj * 16 + r;
            f32x4 a = acc[oi][mj];
            float v0 = a[0] + bias[o], v1 = a[1] + bias[o + 1];
            float v2 = a[2] + bias[o + 2], v3 = a[3] + bias[o + 3];
            if (LAYOUT == 1) {
                *(uint2*)&OUT[((size_t)b * nM + m) * COUT + o] = packb4(v0, v1, v2, v3);
            } else if (LAYOUT == 0) {
                int n = m / 12, t = m - n * 12;
                *(uint2*)&OUT[((size_t)(b * 12 + t) * nN + n) * COUT + o] =
                    packb4(v0, v1, v2, v3);
            } else {
                int n = m / 12, t = m - n * 12;
                size_t bt = (size_t)(b * 12 + t) * 64;
                OUT[(bt + o) * nN + n]     = f2b(v0);
                OUT[(bt + o + 1) * nN + n] = f2b(v1);
                OUT[(bt + o + 2) * nN + n] = f2b(v2);
                OUT[(bt + o + 3) * nN + n] = f2b(v3);
            }
        }
}

// ---------------- node softmax row-sums (no score store; writes reciprocals) -
__global__ __launch_bounds__(256) void rowsum_k(const u16* __restrict__ NQ,
                                                const u16* __restrict__ NK,
                                                const float* __restrict__ Bn,
                                                float* __restrict__ RINV) {
    __shared__ u16 Qt[64 * 72], Kt[64 * 72];
    __shared__ float lsum[64];
    int tid = threadIdx.x;
    int i0 = blockIdx.x * 64, bt = blockIdx.y;
    int lane = tid & 63, wid = tid >> 6;
    int wo = (wid & 1) * 32, wm = (wid >> 1) * 32;
    int quad = lane >> 4, r = lane & 15;
    if (tid < 64) lsum[tid] = 0.f;
    stage64(NQ + ((size_t)bt * nN + i0) * 64, 64, Qt, tid);
    float rsm[2] = {0.f, 0.f};   // per mj (row i = wm + mj*16 + r)
    for (int j0 = 0; j0 < nN; j0 += 64) {
        __syncthreads();
        stage64(NK + ((size_t)bt * nN + j0) * 64, 64, Kt, tid);
        __syncthreads();
        // A = K (rows j), B = Q (rows i): acc[oi][mj][rr] at
        //   j = j0 + wo + oi*16 + quad*4 + rr,  i = i0 + wm + mj*16 + r
        f32x4 acc[2][2] = {};
        mfma_block(Kt, Qt, acc, wo, wm, quad, r);
#pragma unroll
        for (int mj = 0; mj < 2; ++mj) {
            int i_ = i0 + wm + mj * 16 + r;
#pragma unroll
            for (int oi = 0; oi < 2; ++oi) {
                int j_ = j0 + wo + oi * 16 + quad * 4;
                f32x4 b4 = *(const f32x4*)&Bn[(size_t)i_ * nN + j_];
#pragma unroll
                for (int rr = 0; rr < 4; ++rr)
                    rsm[mj] += __expf(acc[oi][mj][rr] * SCALE + b4[rr]);
            }
        }
    }
    // reduce over the 4 quads (they cover different j), rows live on (mj, r)
#pragma unroll
    for (int mj = 0; mj < 2; ++mj) {
        rsm[mj] += __shfl_xor(rsm[mj], 16);
        rsm[mj] += __shfl_xor(rsm[mj], 32);
    }
    if (quad == 0) {
#pragma unroll
        for (int mj = 0; mj < 2; ++mj)
            atomicAdd(&lsum[wm + mj * 16 + r], rsm[mj]);   // combine wo=0/32 waves
    }
    __syncthreads();
    if (tid < 64) RINV[(size_t)bt * nN + i0 + tid] = 1.f / lsum[tid];
}

// ---------------- fused node attention + aggregation (software-pipelined) ----
// Per (w-tile, bt): Kt resident. Per v-tile iteration (2 barriers):
//   phase 1: [issue next-iter Q/V/rinv/adj loads] -> score MFMA -> exp -> Pt
//   phase 2: agg MFMA  ||  ds_write next Qt / Vt[nxt] / rinv
// Every global load is issued >= one phase before its use, so HBM latency
// hides under MFMA + exp instead of serializing the iteration.
__global__ __launch_bounds__(256) void node_agg_fused(const u16* __restrict__ NQ,
                                                      const u16* __restrict__ NK,
                                                      const u16* __restrict__ V1N,
                                                      const float* __restrict__ RINV,
                                                      const float* __restrict__ adj,
                                                      const float* __restrict__ Bn,
                                                      u16* __restrict__ HB) {
    __shared__ u16 Kt[64 * 72], Qt[64 * 72], Vta[64 * 72], Vtb[64 * 72], Pt[64 * 72];
    __shared__ float rinv_s[64];
    int tid = threadIdx.x;
    int w0 = blockIdx.x * 64, bt = blockIdx.y;
    int b = bt / 12, l = bt - b * 12;
    int lane = tid & 63, wid = tid >> 6;
    int wo = (wid & 1) * 32, wm = (wid >> 1) * 32;
    int quad = lane >> 4, r = lane & 15;
    int srow = tid >> 3, skc = (tid & 7) * 8;   // staging coords (rows srow, srow+32)

    const u16* Qg = NQ + (size_t)bt * nN * 64;
    const u16* Vg = V1N + (size_t)bt * 64 * nN;
    const float* Rg = RINV + (size_t)bt * nN;

    // ---- prologue: stage iter-0 tiles, prefetch iter-0 adj regs ----
    stage64(NK + ((size_t)bt * nN + w0) * 64, 64, Kt, tid);
    stage64(Qg, 64, Qt, tid);
    stage64(Vg, nN, Vta, tid);
    if (tid < 64) rinv_s[tid] = Rg[tid];
    float adjc[2][2][4];
#pragma unroll
    for (int oi = 0; oi < 2; ++oi)
#pragma unroll
        for (int mj = 0; mj < 2; ++mj) {
            int vl = wo + oi * 16 + quad * 4;
            int wl = w0 + wm + mj * 16 + r;
#pragma unroll
            for (int rr = 0; rr < 4; ++rr)
                adjc[oi][mj][rr] = adj[((size_t)bt * nN + vl + rr) * nN + wl];
        }
    __syncthreads();

    f32x4 acc2[2][2] = {};
    const u16* vcur = Vta;
    u16* vnxt = Vtb;
#pragma unroll
    for (int i = 0; i < 12; ++i) {
        int v0 = i * 64;
        bool hn = i < 11;
        // --- phase 1a: issue next-iter global loads (regs) ---
        uint4 qreg0 = {}, qreg1 = {}, vreg0 = {}, vreg1 = {};
        float rreg = 0.f;
        float adjn[2][2][4];
        if (hn) {
            int nv0 = v0 + 64;
            qreg0 = *(const uint4*)&Qg[(size_t)(nv0 + srow) * 64 + skc];
            qreg1 = *(const uint4*)&Qg[(size_t)(nv0 + srow + 32) * 64 + skc];
            vreg0 = *(const uint4*)&Vg[(size_t)srow * nN + nv0 + skc];
            vreg1 = *(const uint4*)&Vg[(size_t)(srow + 32) * nN + nv0 + skc];
            if (tid < 64) rreg = Rg[nv0 + tid];
#pragma unroll
            for (int oi = 0; oi < 2; ++oi)
#pragma unroll
                for (int mj = 0; mj < 2; ++mj) {
                    int vl = nv0 + wo + oi * 16 + quad * 4;
                    int wl = w0 + wm + mj * 16 + r;
#pragma unroll
                    for (int rr = 0; rr < 4; ++rr)
                        adjn[oi][mj][rr] = adj[((size_t)bt * nN + vl + rr) * nN + wl];
                }
        }
        // --- phase 1b: Bn loads (L2-hot) for current iter ---
        float bnc[2][2][4];
#pragma unroll
        for (int oi = 0; oi < 2; ++oi)
#pragma unroll
            for (int mj = 0; mj < 2; ++mj) {
                int vl = v0 + wo + oi * 16 + quad * 4;
                int wl = w0 + wm + mj * 16 + r;
#pragma unroll
                for (int rr = 0; rr < 4; ++rr)
                    bnc[oi][mj][rr] = Bn[(size_t)(vl + rr) * nN + wl];
            }
        // --- phase 1c: score MFMA (A=Q rows v, B=K rows w) ---
        f32x4 acc1[2][2] = {};
        mfma_block(Qt, Kt, acc1, wo, wm, quad, r);
        // --- phase 1d: P = exp(s*SCALE+Bn)*adj*rinv -> Pt (transposed [w][v]) -
#pragma unroll
        for (int oi = 0; oi < 2; ++oi)
#pragma unroll
            for (int mj = 0; mj < 2; ++mj) {
                int vl = wo + oi * 16 + quad * 4;
                int wl = wm + mj * 16 + r;
                float pv[4];
#pragma unroll
                for (int rr = 0; rr < 4; ++rr) {
                    float e = __expf(acc1[oi][mj][rr] * SCALE + bnc[oi][mj][rr]);
                    pv[rr] = e * adjc[oi][mj][rr] * rinv_s[vl + rr];
                }
                *(uint2*)&Pt[wl * 72 + vl] = packb4(pv[0], pv[1], pv[2], pv[3]);
            }
        __syncthreads();
        // --- phase 2: agg MFMA (A=V rows c, B=P rows w, k=v)  ||  stage next --
        mfma_block(vcur, Pt, acc2, wo, wm, quad, r);
        if (hn) {
            *(uint4*)&Qt[srow * 72 + skc] = qreg0;
            *(uint4*)&Qt[(srow + 32) * 72 + skc] = qreg1;
            *(uint4*)&vnxt[srow * 72 + skc] = vreg0;
            *(uint4*)&vnxt[(srow + 32) * 72 + skc] = vreg1;
            if (tid < 64) rinv_s[tid] = rreg;
#pragma unroll
            for (int oi = 0; oi < 2; ++oi)
#pragma unroll
                for (int mj = 0; mj < 2; ++mj)
#pragma unroll
                    for (int rr = 0; rr < 4; ++rr)
                        adjc[oi][mj][rr] = adjn[oi][mj][rr];
        }
        { const u16* t = vcur; vcur = vnxt; vnxt = (u16*)t; }
        __syncthreads();
    }
#pragma unroll
    for (int oi = 0; oi < 2; ++oi)
#pragma unroll
        for (int mj = 0; mj < 2; ++mj) {
            int c = wo + oi * 16 + quad * 4;
            int w = w0 + wm + mj * 16 + r;
            f32x4 a = acc2[oi][mj];
            *(uint2*)&HB[((size_t)b * nM + w * 12 + l) * 128 + 64 + c] =
                packb4(a[0], a[1], a[2], a[3]);
        }
}

// ---------------- time attention (tiny) -------------------------------------
__global__ __launch_bounds__(192) void time_attn(const u16* __restrict__ TQ,
                                                 const u16* __restrict__ TK,
                                                 const float* __restrict__ Bt,
                                                 float* __restrict__ AT) {
    int bn = blockIdx.x;  // b*768 + n
    __shared__ float tqs[nT * 64], tks[nT * 64], ss[nT * nT];
    __shared__ float inv_s[nT], max_s[nT];
    int tid = threadIdx.x;
    size_t base = (size_t)bn * nT * 64;
#pragma unroll
    for (int r = 0; r < 4; ++r) {
        int idx = tid + r * 192;
        tqs[idx] = b2f(TQ[base + idx]);
        tks[idx] = b2f(TK[base + idx]);
    }
    __syncthreads();
    if (tid < 144) {
        int i = tid / 12, j = tid % 12;
        float s = 0.f;
#pragma unroll
        for (int h = 0; h < 64; ++h) s += tqs[i * 64 + h] * tks[j * 64 + h];
        ss[tid] = s * SCALE + Bt[i * 12 + j];
    }
    __syncthreads();
    if (tid < 12) {
        float mx = -1e30f;
        for (int j = 0; j < 12; ++j) mx = fmaxf(mx, ss[tid * 12 + j]);
        float sm = 0.f;
        for (int j = 0; j < 12; ++j) sm += expf(ss[tid * 12 + j] - mx);
        max_s[tid] = mx; inv_s[tid] = 1.f / sm;
    }
    __syncthreads();
    if (tid < 144) {
        int i = tid / 12;
        AT[(size_t)bn * 144 + tid] = expf(ss[tid] - max_s[i]) * inv_s[i];
    }
}

// ---------------- time aggregation ------------------------------------------
__global__ __launch_bounds__(256) void time_agg_k(const u16* __restrict__ V1N,
                                                  const float* __restrict__ AT,
                                                  u16* __restrict__ HB) {
    int tid = threadIdx.x;
    int lane = tid & 63, cg = tid >> 6;
    int n = blockIdx.x * 64 + lane;
    int b = blockIdx.y;
    size_t bn = (size_t)b * nN + n;
#pragma unroll 2
    for (int cc = 0; cc < 16; ++cc) {
        int c = cg * 16 + cc;
        float acc[12] = {};
        for (int v = 0; v < 12; ++v) {
            float val = b2f(V1N[((size_t)(b * 12 + v) * 64 + c) * nN + n]);
            const float4* at4 = (const float4*)(AT + bn * 144 + v * 12);
            float4 a0 = at4[0], a1 = at4[1], a2 = at4[2];
            acc[0] += val * a0.x;  acc[1] += val * a0.y;
            acc[2] += val * a0.z;  acc[3] += val * a0.w;
            acc[4] += val * a1.x;  acc[5] += val * a1.y;
            acc[6] += val * a1.z;  acc[7] += val * a1.w;
            acc[8] += val * a2.x;  acc[9] += val * a2.y;
            acc[10] += val * a2.z; acc[11] += val * a2.w;
        }
#pragma unroll
        for (int t = 0; t < 12; ++t)
            HB[((size_t)b * nM + n * 12 + t) * 128 + c] = f2b(acc[t]);
    }
}

// ---------------- proj GEMM on (h .* vg), channels-first fp32 out + residual -
__global__ __launch_bounds__(256) void prodproj_k(const u16* __restrict__ HB,
                                                  const u16* __restrict__ VG,
                                                  const u16* __restrict__ W,
                                                  const float* __restrict__ bias,
                                                  const float* __restrict__ RES,
                                                  float* __restrict__ OUT) {
    __shared__ u16 As[64 * 72], Bs[64 * 72];
    int tid = threadIdx.x;
    int m0 = blockIdx.x * 64, o0 = blockIdx.y * 64, b = blockIdx.z;
    int lane = tid & 63, wid = tid >> 6;
    int wo = (wid & 1) * 32, wm = (wid >> 1) * 32;
    int quad = lane >> 4, r = lane & 15;
    f32x4 acc[2][2] = {};
    for (int k0 = 0; k0 < 128; k0 += 64) {
        __syncthreads();
        stage64(W + (size_t)o0 * 128 + k0, 128, As, tid);
#pragma unroll
        for (int rr = 0; rr < 2; ++rr) {
            int c = tid + rr * 256;
            int row = c >> 3, kc = (c & 7) * 8;
            size_t gi = ((size_t)b * nM + m0 + row) * 128 + k0 + kc;
            uint4 hv = *(const uint4*)&HB[gi];
            uint4 vv = *(const uint4*)&VG[gi];
            u16* hs = (u16*)&hv; u16* vs = (u16*)&vv;
            union { uint4 q; u16 s[8]; } ov;
#pragma unroll
            for (int q2 = 0; q2 < 8; ++q2) ov.s[q2] = f2b(b2f(hs[q2]) * b2f(vs[q2]));
            *(uint4*)&Bs[row * 72 + kc] = ov.q;
        }
        __syncthreads();
        mfma_block(As, Bs, acc, wo, wm, quad, r);
    }
#pragma unroll
    for (int oi = 0; oi < 2; ++oi)
#pragma unroll
        for (int mj = 0; mj < 2; ++mj) {
            int o = o0 + wo + oi * 16 + quad * 4;
            int m = m0 + wm + mj * 16 + r;
            f32x4 a = acc[oi][mj];
#pragma unroll
            for (int rr = 0; rr < 4; ++rr) {
                size_t idx = ((size_t)(b * nC + o + rr)) * nM + m;
                OUT[idx] = a[rr] + bias[o + rr] + RES[idx];
            }
        }
}

// ---------------- FFN1 gated (a * gelu(g)) -> bf16 channels-last ------------
__global__ __launch_bounds__(256) void ffn1_k(const u16* __restrict__ X,
                                              const u16* __restrict__ W1,
                                              const float* __restrict__ B1,
                                              u16* __restrict__ G1) {
    __shared__ u16 As[64 * 72], Gs[64 * 72], Bs[64 * 72];
    int tid = threadIdx.x;
    int m0 = blockIdx.x * 64, o0 = blockIdx.y * 64, b = blockIdx.z;
    int lane = tid & 63, wid = tid >> 6;
    int wo = (wid & 1) * 32, wm = (wid >> 1) * 32;
    int quad = lane >> 4, r = lane & 15;
    f32x4 acca[2][2] = {}, accg[2][2] = {};
    for (int k0 = 0; k0 < 256; k0 += 64) {
        __syncthreads();
        stage64(W1 + (size_t)o0 * 256 + k0, 256, As, tid);
        stage64(W1 + (size_t)(512 + o0) * 256 + k0, 256, Gs, tid);
        stage64(X + ((size_t)b * nM + m0) * 256 + k0, 256, Bs, tid);
        __syncthreads();
#pragma unroll
        for (int ks = 0; ks < 64; ks += 32) {
            bf16x8 a0 = *(const bf16x8*)&As[(wo + r) * 72 + ks + quad * 8];
            bf16x8 a1 = *(const bf16x8*)&As[(wo + 16 + r) * 72 + ks + quad * 8];
            bf16x8 g0 = *(const bf16x8*)&Gs[(wo + r) * 72 + ks + quad * 8];
            bf16x8 g1 = *(const bf16x8*)&Gs[(wo + 16 + r) * 72 + ks + quad * 8];
            bf16x8 b0 = *(const bf16x8*)&Bs[(wm + r) * 72 + ks + quad * 8];
            bf16x8 b1 = *(const bf16x8*)&Bs[(wm + 16 + r) * 72 + ks + quad * 8];
            acca[0][0] = mfma16(a0, b0, acca[0][0]);
            acca[0][1] = mfma16(a0, b1, acca[0][1]);
            acca[1][0] = mfma16(a1, b0, acca[1][0]);
            acca[1][1] = mfma16(a1, b1, acca[1][1]);
            accg[0][0] = mfma16(g0, b0, accg[0][0]);
            accg[0][1] = mfma16(g0, b1, accg[0][1]);
            accg[1][0] = mfma16(g1, b0, accg[1][0]);
            accg[1][1] = mfma16(g1, b1, accg[1][1]);
        }
    }
#pragma unroll
    for (int oi = 0; oi < 2; ++oi)
#pragma unroll
        for (int mj = 0; mj < 2; ++mj) {
            int o = o0 + wo + oi * 16 + quad * 4;
            int m = m0 + wm + mj * 16 + r;
            float vals[4];
#pragma unroll
            for (int rr = 0; rr < 4; ++rr) {
                float aa = acca[oi][mj][rr] + B1[o + rr];
                float gg = accg[oi][mj][rr] + B1[512 + o + rr];
                float gl = 0.5f * gg * (1.f + erff(gg * 0.70710678118654752f));
                vals[rr] = aa * gl;
            }
            *(uint2*)&G1[((size_t)b * nM + m) * 512 + o] =
                packb4(vals[0], vals[1], vals[2], vals[3]);
        }
}

// ---------------- FFN2: channels-first fp32 out + residual ------------------
__global__ __launch_bounds__(256) void ffn2_k(const u16* __restrict__ G1,
                                              const u16* __restrict__ W2,
                                              const float* __restrict__ B2,
                                              const float* __restrict__ RES,
                                              float* __restrict__ OUT) {
    __shared__ u16 As[64 * 72], Bs[64 * 72];
    int tid = threadIdx.x;
    int m0 = blockIdx.x * 64, o0 = blockIdx.y * 64, b = blockIdx.z;
    int lane = tid & 63, wid = tid >> 6;
    int wo = (wid & 1) * 32, wm = (wid >> 1) * 32;
    int quad = lane >> 4, r = lane & 15;
    f32x4 acc[2][2] = {};
    for (int k0 = 0; k0 < 512; k0 += 64) {
        __syncthreads();
        stage64(W2 + (size_t)o0 * 512 + k0, 512, As, tid);
        stage64(G1 + ((size_t)b * nM + m0) * 512 + k0, 512, Bs, tid);
        __syncthreads();
        mfma_block(As, Bs, acc, wo, wm, quad, r);
    }
#pragma unroll
    for (int oi = 0; oi < 2; ++oi)
#pragma unroll
        for (int mj = 0; mj < 2; ++mj) {
            int o = o0 + wo + oi * 16 + quad * 4;
            int m = m0 + wm + mj * 16 + r;
            f32x4 a = acc[oi][mj];
#pragma unroll
            for (int rr = 0; rr < 4; ++rr) {
                size_t idx = ((size_t)(b * nC + o + rr)) * nM + m;
                OUT[idx] = a[rr] + B2[o + rr] + RES[idx];
            }
        }
}

// ---------------------------------------------------------------------------
extern "C" void kernel_launch(void* const* d_in, const int* in_sizes, int n_in,
                              void* d_out, int out_size, void* d_ws, size_t ws_size,
                              hipStream_t stream) {
    const float* x      = (const float*)d_in[0];
    const float* adj    = (const float*)d_in[4];
    const float* ln1w   = (const float*)d_in[5];
    const float* ln1b   = (const float*)d_in[6];
    const float* ln2w   = (const float*)d_in[7];
    const float* ln2b   = (const float*)d_in[8];
    const float* Wnq    = (const float*)d_in[9];
    const float* bnq    = (const float*)d_in[10];
    const float* Wnk    = (const float*)d_in[11];
    const float* bnk    = (const float*)d_in[12];
    const float* Wtq    = (const float*)d_in[13];
    const float* btq    = (const float*)d_in[14];
    const float* Wtk    = (const float*)d_in[15];
    const float* btk    = (const float*)d_in[16];
    const float* Bn     = (const float*)d_in[17];
    const float* Bt     = (const float*)d_in[18];
    const float* v_w    = (const float*)d_in[19];
    const float* v_b    = (const float*)d_in[20];
    const float* fcv_w  = (const float*)d_in[21];
    const float* fcv_b  = (const float*)d_in[22];
    const float* proj_w = (const float*)d_in[23];
    const float* proj_b = (const float*)d_in[24];
    const float* w1     = (const float*)d_in[25];
    const float* b1     = (const float*)d_in[26];
    const float* w2     = (const float*)d_in[27];
    const float* b2     = (const float*)d_in[28];
    float* out = (float*)d_out;

    char* p = (char*)d_ws;
    auto alloc = [&](size_t bytes) { char* q = p; p += (bytes + 255) & ~(size_t)255; return q; };
    u16*   x1cl   = (u16*)alloc(37748736);   // [B][M][256] bf16
    u16*   nqb    = (u16*)alloc(9437184);    // [BT][N][64] / [B][M][64]
    u16*   nkb    = (u16*)alloc(9437184);
    u16*   v1n    = (u16*)alloc(9437184);    // [BT][64][N]
    float* atT    = (float*)alloc(3538944);  // [B][N][12][12]
    u16*   hb     = (u16*)alloc(18874368);   // [B][M][128]
    u16*   vg     = (u16*)alloc(18874368);   // [B][M][128]
    float* rinv   = (float*)alloc(294912);   // [BT][N] reciprocal row-sums
    u16*   WB     = (u16*)alloc(1081344);    // bf16 weights
    float* xr     = (float*)alloc(75497472); // [B][256][M] fp32
    u16*   x2cl   = (u16*)alloc(37748736);   // [B][M][256] bf16
    u16*   g1     = (u16*)alloc(75497472);   // [B][M][512] bf16

    dim3 blk(256);
    cvt_w<<<dim3(2112), blk, 0, stream>>>(Wnq, Wnk, Wtq, Wtk, v_w, fcv_w, proj_w,
                                          w1, w2, WB);
    ln_cl<<<dim3(144, nB), blk, 0, stream>>>(x, ln1w, ln1b, x1cl);
    // --- node attention path (nqb/nkb hold node q/k until node_agg_fused) ---
    gemm_proj<64, 0><<<dim3(144, 1, nB), blk, 0, stream>>>(x1cl, WB + 0, bnq, nqb);
    gemm_proj<64, 0><<<dim3(144, 1, nB), blk, 0, stream>>>(x1cl, WB + 16384, bnk, nkb);
    rowsum_k<<<dim3(12, nB * nT), blk, 0, stream>>>(nqb, nkb, Bn, rinv);
    gemm_proj<64, 2><<<dim3(144, 1, nB), blk, 0, stream>>>(x1cl, WB + 65536, v_b, v1n);
    node_agg_fused<<<dim3(12, nB * nT), blk, 0, stream>>>(nqb, nkb, v1n, rinv,
                                                          adj, Bn, hb);
    // --- time attention path (reuses nqb/nkb) ---
    gemm_proj<64, 1><<<dim3(144, 1, nB), blk, 0, stream>>>(x1cl, WB + 32768, btq, nqb);
    gemm_proj<64, 1><<<dim3(144, 1, nB), blk, 0, stream>>>(x1cl, WB + 49152, btk, nkb);
    time_attn<<<dim3(nB * nN), dim3(192), 0, stream>>>(nqb, nkb, Bt, atT);
    time_agg_k<<<dim3(12, nB), blk, 0, stream>>>(v1n, atT, hb);
    // --- gate, proj, FFN ---
    gemm_proj<128, 1><<<dim3(144, 2, nB), blk, 0, stream>>>(x1cl, WB + 81920, fcv_b, vg);
    prodproj_k<<<dim3(144, 4, nB), blk, 0, stream>>>(hb, vg, WB + 114688, proj_b, x, xr);
    ln_cl<<<dim3(144, nB), blk, 0, stream>>>(xr, ln2w, ln2b, x2cl);
    ffn1_k<<<dim3(144, 8, nB), blk, 0, stream>>>(x2cl, WB + 147456, b1, g1);
    ffn2_k<<<dim3(144, 4, nB), blk, 0, stream>>>(g1, WB + 409600, b2, xr, out);
}

// Round 4
// 837.916 us; speedup vs baseline: 1.2054x; 1.1051x over previous
//
#include <hip/hip_runtime.h>
#include <cstddef>

typedef unsigned short u16;
typedef __attribute__((ext_vector_type(8))) short bf16x8;
typedef __attribute__((ext_vector_type(4))) float f32x4;

constexpr int nB = 8, nC = 256, nN = 768, nT = 12, nM = nN * nT, nH = 64;
constexpr float SCALE = 0.125f;
constexpr float LNEPS = 1e-6f;

// ---------------- bf16 helpers ----------------
__device__ inline u16 f2b(float f) {
    union { float f; unsigned u; } v; v.f = f;
    unsigned r = v.u + 0x7FFFu + ((v.u >> 16) & 1u);
    return (u16)(r >> 16);
}
__device__ inline float b2f(u16 h) {
    union { unsigned u; float f; } v; v.u = ((unsigned)h) << 16;
    return v.f;
}
__device__ inline uint2 packb4(float a, float b, float c, float d) {
    uint2 r;
    r.x = (unsigned)f2b(a) | ((unsigned)f2b(b) << 16);
    r.y = (unsigned)f2b(c) | ((unsigned)f2b(d) << 16);
    return r;
}
__device__ inline f32x4 mfma16(bf16x8 a, bf16x8 b, f32x4 c) {
    return __builtin_amdgcn_mfma_f32_16x16x32_bf16(a, b, c, 0, 0, 0);
}

// Stage a 64x64 bf16 tile (row stride ld elements) into LDS [64][72].
__device__ inline void stage64(const u16* __restrict__ g, int ld, u16* lds, int tid) {
#pragma unroll
    for (int r = 0; r < 2; ++r) {
        int c = tid + r * 256;
        int row = c >> 3, kc = (c & 7) * 8;
        *(uint4*)&lds[row * 72 + kc] = *(const uint4*)&g[(size_t)row * ld + kc];
    }
}

// One 64-wide K-chunk of MFMA compute. acc[2][2] over (o-sub, m-sub) 16x16 tiles.
// Output element: A-row = wo + oi*16 + quad*4 + rr (contiguous rr),
//                 B-row = wm + mj*16 + r (lane-fast r).
__device__ inline void mfma_block(const u16* As, const u16* Bs, f32x4 acc[2][2],
                                  int wo, int wm, int quad, int r) {
#pragma unroll
    for (int ks = 0; ks < 64; ks += 32) {
        bf16x8 a0 = *(const bf16x8*)&As[(wo + r) * 72 + ks + quad * 8];
        bf16x8 a1 = *(const bf16x8*)&As[(wo + 16 + r) * 72 + ks + quad * 8];
        bf16x8 b0 = *(const bf16x8*)&Bs[(wm + r) * 72 + ks + quad * 8];
        bf16x8 b1 = *(const bf16x8*)&Bs[(wm + 16 + r) * 72 + ks + quad * 8];
        acc[0][0] = mfma16(a0, b0, acc[0][0]);
        acc[0][1] = mfma16(a0, b1, acc[0][1]);
        acc[1][0] = mfma16(a1, b0, acc[1][0]);
        acc[1][1] = mfma16(a1, b1, acc[1][1]);
    }
}

// ---------------- weight conversion (fp32 -> bf16, with q/k transposes) ------
// Layout in WB (u16): wq@0 wk@16384 wtq@32768 wtk@49152 wv@65536 wfcv@81920
//                     wproj@114688 wf1@147456 wf2@409600, total 540672
__global__ __launch_bounds__(256) void cvt_w(const float* __restrict__ Wnq,
                                             const float* __restrict__ Wnk,
                                             const float* __restrict__ Wtq,
                                             const float* __restrict__ Wtk,
                                             const float* __restrict__ vw,
                                             const float* __restrict__ fcvw,
                                             const float* __restrict__ projw,
                                             const float* __restrict__ w1,
                                             const float* __restrict__ w2,
                                             u16* __restrict__ WB) {
    int i = blockIdx.x * 256 + threadIdx.x;
    float v;
    if (i < 65536) {
        int seg = i >> 14, j = i & 16383;
        int o = j >> 8, k = j & 255;
        const float* src = seg == 0 ? Wnq : seg == 1 ? Wnk : seg == 2 ? Wtq : Wtk;
        v = src[k * 64 + o];                       // [c][h] -> [h][c]
    } else if (i < 81920)  v = vw[i - 65536];
    else if (i < 114688)   v = fcvw[i - 81920];
    else if (i < 147456)   v = projw[i - 114688];
    else if (i < 409600)   v = w1[i - 147456];
    else                   v = w2[i - 409600];
    WB[i] = f2b(v);
}

// ---------------- LayerNorm (channels-first fp32 in, channels-last bf16 out) --
__global__ __launch_bounds__(256) void ln_cl(const float* __restrict__ X,
                                             const float* __restrict__ w,
                                             const float* __restrict__ bias,
                                             u16* __restrict__ Y) {
    int tid = threadIdx.x;
    int lane = tid & 63, cg = tid >> 6;
    int m0 = blockIdx.x * 64, b = blockIdx.y;
    size_t base = (size_t)b * nC * nM + m0 + lane;
    float s = 0.f, ss = 0.f;
#pragma unroll 4
    for (int k = 0; k < 64; ++k) {
        float v = X[base + (size_t)(cg * 64 + k) * nM];
        s += v; ss += v * v;
    }
    __shared__ float rs[4][64], rss[4][64], mu_s[64], rstd_s[64];
    __shared__ u16 Lo[64][264];
    rs[cg][lane] = s; rss[cg][lane] = ss;
    __syncthreads();
    if (tid < 64) {
        float t1 = rs[0][lane] + rs[1][lane] + rs[2][lane] + rs[3][lane];
        float t2 = rss[0][lane] + rss[1][lane] + rss[2][lane] + rss[3][lane];
        float mu = t1 * (1.f / nC);
        float var = t2 * (1.f / nC) - mu * mu;
        mu_s[lane] = mu;
        rstd_s[lane] = rsqrtf(var + LNEPS);
    }
    __syncthreads();
    float mu = mu_s[lane], rstd = rstd_s[lane];
#pragma unroll 8
    for (int k = 0; k < 64; k += 2) {
        int c = cg * 64 + k;
        float v0 = (X[base + (size_t)c * nM] - mu) * rstd * w[c] + bias[c];
        float v1 = (X[base + (size_t)(c + 1) * nM] - mu) * rstd * w[c + 1] + bias[c + 1];
        *(unsigned*)&Lo[lane][c] = (unsigned)f2b(v0) | ((unsigned)f2b(v1) << 16);
    }
    __syncthreads();
#pragma unroll
    for (int r = 0; r < 8; ++r) {
        int c = tid + r * 256;
        int mm = c >> 5, ch = (c & 31) * 8;
        *(uint4*)&Y[((size_t)b * nM + m0 + mm) * 256 + ch] = *(uint4*)&Lo[mm][ch];
    }
}

// ---------------- generic projection GEMM (X channels-last, K=256) ----------
// LAYOUT 0: OUT[(b*12+t)][n][COUT] (nq/nk)   1: OUT[b][m][COUT] (tq/tk/fcv)
//        2: OUT[(b*12+t)][o][n] (v1)
template <int COUT, int LAYOUT>
__global__ __launch_bounds__(256) void gemm_proj(const u16* __restrict__ X,
                                                 const u16* __restrict__ W,
                                                 const float* __restrict__ bias,
                                                 u16* __restrict__ OUT) {
    __shared__ u16 As[64 * 72], Bs[64 * 72];
    int tid = threadIdx.x;
    int m0 = blockIdx.x * 64, o0 = blockIdx.y * 64, b = blockIdx.z;
    int lane = tid & 63, wid = tid >> 6;
    int wo = (wid & 1) * 32, wm = (wid >> 1) * 32;
    int quad = lane >> 4, r = lane & 15;
    const u16* Ag = W + (size_t)o0 * 256;
    const u16* Bg = X + ((size_t)b * nM + m0) * 256;
    f32x4 acc[2][2] = {};
    for (int k0 = 0; k0 < 256; k0 += 64) {
        __syncthreads();
        stage64(Ag + k0, 256, As, tid);
        stage64(Bg + k0, 256, Bs, tid);
        __syncthreads();
        mfma_block(As, Bs, acc, wo, wm, quad, r);
    }
#pragma unroll
    for (int oi = 0; oi < 2; ++oi)
#pragma unroll
        for (int mj = 0; mj < 2; ++mj) {
            int o = o0 + wo + oi * 16 + quad * 4;
            int m = m0 + wm + mj * 16 + r;
            f32x4 a = acc[oi][mj];
            float v0 = a[0] + bias[o], v1 = a[1] + bias[o + 1];
            float v2 = a[2] + bias[o + 2], v3 = a[3] + bias[o + 3];
            if (LAYOUT == 1) {
                *(uint2*)&OUT[((size_t)b * nM + m) * COUT + o] = packb4(v0, v1, v2, v3);
            } else if (LAYOUT == 0) {
                int n = m / 12, t = m - n * 12;
                *(uint2*)&OUT[((size_t)(b * 12 + t) * nN + n) * COUT + o] =
                    packb4(v0, v1, v2, v3);
            } else {
                int n = m / 12, t = m - n * 12;
                size_t bt = (size_t)(b * 12 + t) * 64;
                OUT[(bt + o) * nN + n]     = f2b(v0);
                OUT[(bt + o + 1) * nN + n] = f2b(v1);
                OUT[(bt + o + 2) * nN + n] = f2b(v2);
                OUT[(bt + o + 3) * nN + n] = f2b(v3);
            }
        }
}

// ---------------- node softmax row-sums (no score store; writes reciprocals) -
__global__ __launch_bounds__(256) void rowsum_k(const u16* __restrict__ NQ,
                                                const u16* __restrict__ NK,
                                                const float* __restrict__ Bn,
                                                float* __restrict__ RINV) {
    __shared__ u16 Qt[64 * 72], Kt[64 * 72];
    __shared__ float lsum[64];
    int tid = threadIdx.x;
    int i0 = blockIdx.x * 64, bt = blockIdx.y;
    int lane = tid & 63, wid = tid >> 6;
    int wo = (wid & 1) * 32, wm = (wid >> 1) * 32;
    int quad = lane >> 4, r = lane & 15;
    if (tid < 64) lsum[tid] = 0.f;
    stage64(NQ + ((size_t)bt * nN + i0) * 64, 64, Qt, tid);
    float rsm[2] = {0.f, 0.f};   // per mj (row i = wm + mj*16 + r)
    for (int j0 = 0; j0 < nN; j0 += 64) {
        __syncthreads();
        stage64(NK + ((size_t)bt * nN + j0) * 64, 64, Kt, tid);
        __syncthreads();
        // A = K (rows j), B = Q (rows i): acc[oi][mj][rr] at
        //   j = j0 + wo + oi*16 + quad*4 + rr,  i = i0 + wm + mj*16 + r
        f32x4 acc[2][2] = {};
        mfma_block(Kt, Qt, acc, wo, wm, quad, r);
#pragma unroll
        for (int mj = 0; mj < 2; ++mj) {
            int i_ = i0 + wm + mj * 16 + r;
#pragma unroll
            for (int oi = 0; oi < 2; ++oi) {
                int j_ = j0 + wo + oi * 16 + quad * 4;
                f32x4 b4 = *(const f32x4*)&Bn[(size_t)i_ * nN + j_];
#pragma unroll
                for (int rr = 0; rr < 4; ++rr)
                    rsm[mj] += __expf(acc[oi][mj][rr] * SCALE + b4[rr]);
            }
        }
    }
    // reduce over the 4 quads (they cover different j), rows live on (mj, r)
#pragma unroll
    for (int mj = 0; mj < 2; ++mj) {
        rsm[mj] += __shfl_xor(rsm[mj], 16);
        rsm[mj] += __shfl_xor(rsm[mj], 32);
    }
    if (quad == 0) {
#pragma unroll
        for (int mj = 0; mj < 2; ++mj)
            atomicAdd(&lsum[wm + mj * 16 + r], rsm[mj]);   // combine wo=0/32 waves
    }
    __syncthreads();
    if (tid < 64) RINV[(size_t)bt * nN + i0 + tid] = 1.f / lsum[tid];
}

// ---------------- fused node attention + aggregation (software-pipelined) ----
// Per (w-tile, bt): Kt resident. Per v-tile iteration (2 barriers):
//   phase 1: [issue next-iter Q/V/rinv/adj loads] -> score MFMA -> exp -> Pt
//   phase 2: agg MFMA  ||  ds_write next Qt / Vt[nxt] / rinv
// Every global load is issued >= one phase before its use, so HBM latency
// hides under MFMA + exp instead of serializing the iteration.
__global__ __launch_bounds__(256) void node_agg_fused(const u16* __restrict__ NQ,
                                                      const u16* __restrict__ NK,
                                                      const u16* __restrict__ V1N,
                                                      const float* __restrict__ RINV,
                                                      const float* __restrict__ adj,
                                                      const float* __restrict__ Bn,
                                                      u16* __restrict__ HB) {
    __shared__ u16 Kt[64 * 72], Qt[64 * 72], Vta[64 * 72], Vtb[64 * 72], Pt[64 * 72];
    __shared__ float rinv_s[64];
    int tid = threadIdx.x;
    int w0 = blockIdx.x * 64, bt = blockIdx.y;
    int b = bt / 12, l = bt - b * 12;
    int lane = tid & 63, wid = tid >> 6;
    int wo = (wid & 1) * 32, wm = (wid >> 1) * 32;
    int quad = lane >> 4, r = lane & 15;
    int srow = tid >> 3, skc = (tid & 7) * 8;   // staging coords (rows srow, srow+32)

    const u16* Qg = NQ + (size_t)bt * nN * 64;
    const u16* Vg = V1N + (size_t)bt * 64 * nN;
    const float* Rg = RINV + (size_t)bt * nN;

    // ---- prologue: stage iter-0 tiles, prefetch iter-0 adj regs ----
    stage64(NK + ((size_t)bt * nN + w0) * 64, 64, Kt, tid);
    stage64(Qg, 64, Qt, tid);
    stage64(Vg, nN, Vta, tid);
    if (tid < 64) rinv_s[tid] = Rg[tid];
    float adjc[2][2][4];
#pragma unroll
    for (int oi = 0; oi < 2; ++oi)
#pragma unroll
        for (int mj = 0; mj < 2; ++mj) {
            int vl = wo + oi * 16 + quad * 4;
            int wl = w0 + wm + mj * 16 + r;
#pragma unroll
            for (int rr = 0; rr < 4; ++rr)
                adjc[oi][mj][rr] = adj[((size_t)bt * nN + vl + rr) * nN + wl];
        }
    __syncthreads();

    f32x4 acc2[2][2] = {};
    const u16* vcur = Vta;
    u16* vnxt = Vtb;
#pragma unroll
    for (int i = 0; i < 12; ++i) {
        int v0 = i * 64;
        bool hn = i < 11;
        // --- phase 1a: issue next-iter global loads (regs) ---
        uint4 qreg0 = {}, qreg1 = {}, vreg0 = {}, vreg1 = {};
        float rreg = 0.f;
        float adjn[2][2][4];
        if (hn) {
            int nv0 = v0 + 64;
            qreg0 = *(const uint4*)&Qg[(size_t)(nv0 + srow) * 64 + skc];
            qreg1 = *(const uint4*)&Qg[(size_t)(nv0 + srow + 32) * 64 + skc];
            vreg0 = *(const uint4*)&Vg[(size_t)srow * nN + nv0 + skc];
            vreg1 = *(const uint4*)&Vg[(size_t)(srow + 32) * nN + nv0 + skc];
            if (tid < 64) rreg = Rg[nv0 + tid];
#pragma unroll
            for (int oi = 0; oi < 2; ++oi)
#pragma unroll
                for (int mj = 0; mj < 2; ++mj) {
                    int vl = nv0 + wo + oi * 16 + quad * 4;
                    int wl = w0 + wm + mj * 16 + r;
#pragma unroll
                    for (int rr = 0; rr < 4; ++rr)
                        adjn[oi][mj][rr] = adj[((size_t)bt * nN + vl + rr) * nN + wl];
                }
        }
        // --- phase 1b: Bn loads (L2-hot) for current iter ---
        float bnc[2][2][4];
#pragma unroll
        for (int oi = 0; oi < 2; ++oi)
#pragma unroll
            for (int mj = 0; mj < 2; ++mj) {
                int vl = v0 + wo + oi * 16 + quad * 4;
                int wl = w0 + wm + mj * 16 + r;
#pragma unroll
                for (int rr = 0; rr < 4; ++rr)
                    bnc[oi][mj][rr] = Bn[(size_t)(vl + rr) * nN + wl];
            }
        // --- phase 1c: score MFMA (A=Q rows v, B=K rows w) ---
        f32x4 acc1[2][2] = {};
        mfma_block(Qt, Kt, acc1, wo, wm, quad, r);
        // --- phase 1d: P = exp(s*SCALE+Bn)*adj*rinv -> Pt (transposed [w][v]) -
#pragma unroll
        for (int oi = 0; oi < 2; ++oi)
#pragma unroll
            for (int mj = 0; mj < 2; ++mj) {
                int vl = wo + oi * 16 + quad * 4;
                int wl = wm + mj * 16 + r;
                float pv[4];
#pragma unroll
                for (int rr = 0; rr < 4; ++rr) {
                    float e = __expf(acc1[oi][mj][rr] * SCALE + bnc[oi][mj][rr]);
                    pv[rr] = e * adjc[oi][mj][rr] * rinv_s[vl + rr];
                }
                *(uint2*)&Pt[wl * 72 + vl] = packb4(pv[0], pv[1], pv[2], pv[3]);
            }
        __syncthreads();
        // --- phase 2: agg MFMA (A=V rows c, B=P rows w, k=v)  ||  stage next --
        mfma_block(vcur, Pt, acc2, wo, wm, quad, r);
        if (hn) {
            *(uint4*)&Qt[srow * 72 + skc] = qreg0;
            *(uint4*)&Qt[(srow + 32) * 72 + skc] = qreg1;
            *(uint4*)&vnxt[srow * 72 + skc] = vreg0;
            *(uint4*)&vnxt[(srow + 32) * 72 + skc] = vreg1;
            if (tid < 64) rinv_s[tid] = rreg;
#pragma unroll
            for (int oi = 0; oi < 2; ++oi)
#pragma unroll
                for (int mj = 0; mj < 2; ++mj)
#pragma unroll
                    for (int rr = 0; rr < 4; ++rr)
                        adjc[oi][mj][rr] = adjn[oi][mj][rr];
        }
        { const u16* t = vcur; vcur = vnxt; vnxt = (u16*)t; }
        __syncthreads();
    }
#pragma unroll
    for (int oi = 0; oi < 2; ++oi)
#pragma unroll
        for (int mj = 0; mj < 2; ++mj) {
            int c = wo + oi * 16 + quad * 4;
            int w = w0 + wm + mj * 16 + r;
            f32x4 a = acc2[oi][mj];
            *(uint2*)&HB[((size_t)b * nM + w * 12 + l) * 128 + 64 + c] =
                packb4(a[0], a[1], a[2], a[3]);
        }
}

// ---------------- time attention (tiny) -------------------------------------
__global__ __launch_bounds__(192) void time_attn(const u16* __restrict__ TQ,
                                                 const u16* __restrict__ TK,
                                                 const float* __restrict__ Bt,
                                                 float* __restrict__ AT) {
    int bn = blockIdx.x;  // b*768 + n
    __shared__ float tqs[nT * 64], tks[nT * 64], ss[nT * nT];
    __shared__ float inv_s[nT], max_s[nT];
    int tid = threadIdx.x;
    size_t base = (size_t)bn * nT * 64;
#pragma unroll
    for (int r = 0; r < 4; ++r) {
        int idx = tid + r * 192;
        tqs[idx] = b2f(TQ[base + idx]);
        tks[idx] = b2f(TK[base + idx]);
    }
    __syncthreads();
    if (tid < 144) {
        int i = tid / 12, j = tid % 12;
        float s = 0.f;
#pragma unroll
        for (int h = 0; h < 64; ++h) s += tqs[i * 64 + h] * tks[j * 64 + h];
        ss[tid] = s * SCALE + Bt[i * 12 + j];
    }
    __syncthreads();
    if (tid < 12) {
        float mx = -1e30f;
        for (int j = 0; j < 12; ++j) mx = fmaxf(mx, ss[tid * 12 + j]);
        float sm = 0.f;
        for (int j = 0; j < 12; ++j) sm += expf(ss[tid * 12 + j] - mx);
        max_s[tid] = mx; inv_s[tid] = 1.f / sm;
    }
    __syncthreads();
    if (tid < 144) {
        int i = tid / 12;
        AT[(size_t)bn * 144 + tid] = expf(ss[tid] - max_s[i]) * inv_s[i];
    }
}

// ---------------- time aggregation (write-coalesced via LDS transpose) -------
// Grid (48, nB): block handles 16 n x 64 c x 12 t for one b.
// Reads v1n n-lane-fast (coalesced); accumulates acc[4c][12t] in regs;
// transposes through LDS; writes HB half-rows as contiguous uint4 full lines.
__global__ __launch_bounds__(256) void time_agg_k(const u16* __restrict__ V1N,
                                                  const float* __restrict__ AT,
                                                  u16* __restrict__ HB) {
    __shared__ float ats[16][144];     // [n_local][v*12+t]
    __shared__ u16 Lo[16][12][64];     // [n_local][t][c]
    int tid = threadIdx.x;
    int b = blockIdx.y;
    int n0 = blockIdx.x * 16;
    {
        const float* src = AT + ((size_t)b * nN + n0) * 144;
#pragma unroll
        for (int i = 0; i < 9; ++i) {
            int idx = tid + i * 256;
            ats[idx / 144][idx % 144] = src[idx];
        }
    }
    __syncthreads();
    int nl = tid & 15, cg = tid >> 4;          // n lane-fast for coalesced reads
    int n = n0 + nl;
    const u16* vbase = V1N + (size_t)b * 12 * 64 * nN;
    float acc[4][12] = {};
#pragma unroll
    for (int v = 0; v < 12; ++v) {
        float a[12];
#pragma unroll
        for (int t = 0; t < 12; ++t) a[t] = ats[nl][v * 12 + t];
#pragma unroll
        for (int ci = 0; ci < 4; ++ci) {
            float val = b2f(vbase[(size_t)(v * 64 + cg * 4 + ci) * nN + n]);
#pragma unroll
            for (int t = 0; t < 12; ++t) acc[ci][t] += val * a[t];
        }
    }
#pragma unroll
    for (int t = 0; t < 12; ++t)
        *(uint2*)&Lo[nl][t][cg * 4] =
            packb4(acc[0][t], acc[1][t], acc[2][t], acc[3][t]);
    __syncthreads();
    // cooperative write: 192 half-rows (128B each) = 1536 uint4
    int row = tid >> 3, q = tid & 7;
#pragma unroll
    for (int i = 0; i < 6; ++i) {
        int rr = row + i * 32;                 // 0..191
        int nl2 = rr / 12, t2 = rr - nl2 * 12;
        *(uint4*)&HB[((size_t)b * nM + (size_t)(n0 + nl2) * 12 + t2) * 128 + q * 8] =
            *(uint4*)&Lo[nl2][t2][q * 8];
    }
}

// ---------------- proj GEMM on (h .* vg), channels-first fp32 out + residual -
__global__ __launch_bounds__(256) void prodproj_k(const u16* __restrict__ HB,
                                                  const u16* __restrict__ VG,
                                                  const u16* __restrict__ W,
                                                  const float* __restrict__ bias,
                                                  const float* __restrict__ RES,
                                                  float* __restrict__ OUT) {
    __shared__ u16 As[64 * 72], Bs[64 * 72];
    int tid = threadIdx.x;
    int m0 = blockIdx.x * 64, o0 = blockIdx.y * 64, b = blockIdx.z;
    int lane = tid & 63, wid = tid >> 6;
    int wo = (wid & 1) * 32, wm = (wid >> 1) * 32;
    int quad = lane >> 4, r = lane & 15;
    f32x4 acc[2][2] = {};
    for (int k0 = 0; k0 < 128; k0 += 64) {
        __syncthreads();
        stage64(W + (size_t)o0 * 128 + k0, 128, As, tid);
#pragma unroll
        for (int rr = 0; rr < 2; ++rr) {
            int c = tid + rr * 256;
            int row = c >> 3, kc = (c & 7) * 8;
            size_t gi = ((size_t)b * nM + m0 + row) * 128 + k0 + kc;
            uint4 hv = *(const uint4*)&HB[gi];
            uint4 vv = *(const uint4*)&VG[gi];
            u16* hs = (u16*)&hv; u16* vs = (u16*)&vv;
            union { uint4 q; u16 s[8]; } ov;
#pragma unroll
            for (int q2 = 0; q2 < 8; ++q2) ov.s[q2] = f2b(b2f(hs[q2]) * b2f(vs[q2]));
            *(uint4*)&Bs[row * 72 + kc] = ov.q;
        }
        __syncthreads();
        mfma_block(As, Bs, acc, wo, wm, quad, r);
    }
#pragma unroll
    for (int oi = 0; oi < 2; ++oi)
#pragma unroll
        for (int mj = 0; mj < 2; ++mj) {
            int o = o0 + wo + oi * 16 + quad * 4;
            int m = m0 + wm + mj * 16 + r;
            f32x4 a = acc[oi][mj];
#pragma unroll
            for (int rr = 0; rr < 4; ++rr) {
                size_t idx = ((size_t)(b * nC + o + rr)) * nM + m;
                OUT[idx] = a[rr] + bias[o + rr] + RES[idx];
            }
        }
}

// ---------------- FFN1 gated (a * gelu(g)) -> bf16 channels-last ------------
__global__ __launch_bounds__(256) void ffn1_k(const u16* __restrict__ X,
                                              const u16* __restrict__ W1,
                                              const float* __restrict__ B1,
                                              u16* __restrict__ G1) {
    __shared__ u16 As[64 * 72], Gs[64 * 72], Bs[64 * 72];
    int tid = threadIdx.x;
    int m0 = blockIdx.x * 64, o0 = blockIdx.y * 64, b = blockIdx.z;
    int lane = tid & 63, wid = tid >> 6;
    int wo = (wid & 1) * 32, wm = (wid >> 1) * 32;
    int quad = lane >> 4, r = lane & 15;
    f32x4 acca[2][2] = {}, accg[2][2] = {};
    for (int k0 = 0; k0 < 256; k0 += 64) {
        __syncthreads();
        stage64(W1 + (size_t)o0 * 256 + k0, 256, As, tid);
        stage64(W1 + (size_t)(512 + o0) * 256 + k0, 256, Gs, tid);
        stage64(X + ((size_t)b * nM + m0) * 256 + k0, 256, Bs, tid);
        __syncthreads();
#pragma unroll
        for (int ks = 0; ks < 64; ks += 32) {
            bf16x8 a0 = *(const bf16x8*)&As[(wo + r) * 72 + ks + quad * 8];
            bf16x8 a1 = *(const bf16x8*)&As[(wo + 16 + r) * 72 + ks + quad * 8];
            bf16x8 g0 = *(const bf16x8*)&Gs[(wo + r) * 72 + ks + quad * 8];
            bf16x8 g1 = *(const bf16x8*)&Gs[(wo + 16 + r) * 72 + ks + quad * 8];
            bf16x8 b0 = *(const bf16x8*)&Bs[(wm + r) * 72 + ks + quad * 8];
            bf16x8 b1 = *(const bf16x8*)&Bs[(wm + 16 + r) * 72 + ks + quad * 8];
            acca[0][0] = mfma16(a0, b0, acca[0][0]);
            acca[0][1] = mfma16(a0, b1, acca[0][1]);
            acca[1][0] = mfma16(a1, b0, acca[1][0]);
            acca[1][1] = mfma16(a1, b1, acca[1][1]);
            accg[0][0] = mfma16(g0, b0, accg[0][0]);
            accg[0][1] = mfma16(g0, b1, accg[0][1]);
            accg[1][0] = mfma16(g1, b0, accg[1][0]);
            accg[1][1] = mfma16(g1, b1, accg[1][1]);
        }
    }
#pragma unroll
    for (int oi = 0; oi < 2; ++oi)
#pragma unroll
        for (int mj = 0; mj < 2; ++mj) {
            int o = o0 + wo + oi * 16 + quad * 4;
            int m = m0 + wm + mj * 16 + r;
            float vals[4];
#pragma unroll
            for (int rr = 0; rr < 4; ++rr) {
                float aa = acca[oi][mj][rr] + B1[o + rr];
                float gg = accg[oi][mj][rr] + B1[512 + o + rr];
                float gl = 0.5f * gg * (1.f + erff(gg * 0.70710678118654752f));
                vals[rr] = aa * gl;
            }
            *(uint2*)&G1[((size_t)b * nM + m) * 512 + o] =
                packb4(vals[0], vals[1], vals[2], vals[3]);
        }
}

// ---------------- FFN2: channels-first fp32 out + residual ------------------
__global__ __launch_bounds__(256) void ffn2_k(const u16* __restrict__ G1,
                                              const u16* __restrict__ W2,
                                              const float* __restrict__ B2,
                                              const float* __restrict__ RES,
                                              float* __restrict__ OUT) {
    __shared__ u16 As[64 * 72], Bs[64 * 72];
    int tid = threadIdx.x;
    int m0 = blockIdx.x * 64, o0 = blockIdx.y * 64, b = blockIdx.z;
    int lane = tid & 63, wid = tid >> 6;
    int wo = (wid & 1) * 32, wm = (wid >> 1) * 32;
    int quad = lane >> 4, r = lane & 15;
    f32x4 acc[2][2] = {};
    for (int k0 = 0; k0 < 512; k0 += 64) {
        __syncthreads();
        stage64(W2 + (size_t)o0 * 512 + k0, 512, As, tid);
        stage64(G1 + ((size_t)b * nM + m0) * 512 + k0, 512, Bs, tid);
        __syncthreads();
        mfma_block(As, Bs, acc, wo, wm, quad, r);
    }
#pragma unroll
    for (int oi = 0; oi < 2; ++oi)
#pragma unroll
        for (int mj = 0; mj < 2; ++mj) {
            int o = o0 + wo + oi * 16 + quad * 4;
            int m = m0 + wm + mj * 16 + r;
            f32x4 a = acc[oi][mj];
#pragma unroll
            for (int rr = 0; rr < 4; ++rr) {
                size_t idx = ((size_t)(b * nC + o + rr)) * nM + m;
                OUT[idx] = a[rr] + B2[o + rr] + RES[idx];
            }
        }
}

// ---------------------------------------------------------------------------
extern "C" void kernel_launch(void* const* d_in, const int* in_sizes, int n_in,
                              void* d_out, int out_size, void* d_ws, size_t ws_size,
                              hipStream_t stream) {
    const float* x      = (const float*)d_in[0];
    const float* adj    = (const float*)d_in[4];
    const float* ln1w   = (const float*)d_in[5];
    const float* ln1b   = (const float*)d_in[6];
    const float* ln2w   = (const float*)d_in[7];
    const float* ln2b   = (const float*)d_in[8];
    const float* Wnq    = (const float*)d_in[9];
    const float* bnq    = (const float*)d_in[10];
    const float* Wnk    = (const float*)d_in[11];
    const float* bnk    = (const float*)d_in[12];
    const float* Wtq    = (const float*)d_in[13];
    const float* btq    = (const float*)d_in[14];
    const float* Wtk    = (const float*)d_in[15];
    const float* btk    = (const float*)d_in[16];
    const float* Bn     = (const float*)d_in[17];
    const float* Bt     = (const float*)d_in[18];
    const float* v_w    = (const float*)d_in[19];
    const float* v_b    = (const float*)d_in[20];
    const float* fcv_w  = (const float*)d_in[21];
    const float* fcv_b  = (const float*)d_in[22];
    const float* proj_w = (const float*)d_in[23];
    const float* proj_b = (const float*)d_in[24];
    const float* w1     = (const float*)d_in[25];
    const float* b1     = (const float*)d_in[26];
    const float* w2     = (const float*)d_in[27];
    const float* b2     = (const float*)d_in[28];
    float* out = (float*)d_out;

    char* p = (char*)d_ws;
    auto alloc = [&](size_t bytes) { char* q = p; p += (bytes + 255) & ~(size_t)255; return q; };
    u16*   x1cl   = (u16*)alloc(37748736);   // [B][M][256] bf16
    u16*   nqb    = (u16*)alloc(9437184);    // [BT][N][64] / [B][M][64]
    u16*   nkb    = (u16*)alloc(9437184);
    u16*   v1n    = (u16*)alloc(9437184);    // [BT][64][N]
    float* atT    = (float*)alloc(3538944);  // [B][N][12][12]
    u16*   hb     = (u16*)alloc(18874368);   // [B][M][128]
    u16*   vg     = (u16*)alloc(18874368);   // [B][M][128]
    float* rinv   = (float*)alloc(294912);   // [BT][N] reciprocal row-sums
    u16*   WB     = (u16*)alloc(1081344);    // bf16 weights
    float* xr     = (float*)alloc(75497472); // [B][256][M] fp32
    u16*   x2cl   = (u16*)alloc(37748736);   // [B][M][256] bf16
    u16*   g1     = (u16*)alloc(75497472);   // [B][M][512] bf16

    dim3 blk(256);
    cvt_w<<<dim3(2112), blk, 0, stream>>>(Wnq, Wnk, Wtq, Wtk, v_w, fcv_w, proj_w,
                                          w1, w2, WB);
    ln_cl<<<dim3(144, nB), blk, 0, stream>>>(x, ln1w, ln1b, x1cl);
    // --- node attention path (nqb/nkb hold node q/k until node_agg_fused) ---
    gemm_proj<64, 0><<<dim3(144, 1, nB), blk, 0, stream>>>(x1cl, WB + 0, bnq, nqb);
    gemm_proj<64, 0><<<dim3(144, 1, nB), blk, 0, stream>>>(x1cl, WB + 16384, bnk, nkb);
    rowsum_k<<<dim3(12, nB * nT), blk, 0, stream>>>(nqb, nkb, Bn, rinv);
    gemm_proj<64, 2><<<dim3(144, 1, nB), blk, 0, stream>>>(x1cl, WB + 65536, v_b, v1n);
    node_agg_fused<<<dim3(12, nB * nT), blk, 0, stream>>>(nqb, nkb, v1n, rinv,
                                                          adj, Bn, hb);
    // --- time attention path (reuses nqb/nkb) ---
    gemm_proj<64, 1><<<dim3(144, 1, nB), blk, 0, stream>>>(x1cl, WB + 32768, btq, nqb);
    gemm_proj<64, 1><<<dim3(144, 1, nB), blk, 0, stream>>>(x1cl, WB + 49152, btk, nkb);
    time_attn<<<dim3(nB * nN), dim3(192), 0, stream>>>(nqb, nkb, Bt, atT);
    time_agg_k<<<dim3(48, nB), blk, 0, stream>>>(v1n, atT, hb);
    // --- gate, proj, FFN ---
    gemm_proj<128, 1><<<dim3(144, 2, nB), blk, 0, stream>>>(x1cl, WB + 81920, fcv_b, vg);
    prodproj_k<<<dim3(144, 4, nB), blk, 0, stream>>>(hb, vg, WB + 114688, proj_b, x, xr);
    ln_cl<<<dim3(144, nB), blk, 0, stream>>>(xr, ln2w, ln2b, x2cl);
    ffn1_k<<<dim3(144, 8, nB), blk, 0, stream>>>(x2cl, WB + 147456, b1, g1);
    ffn2_k<<<dim3(144, 4, nB), blk, 0, stream>>>(g1, WB + 409600, b2, xr, out);
}